// Round 3
// baseline (54.883 us; speedup 1.0000x reference)
//
#include <hip/hip_runtime.h>
#include <hip/hip_bf16.h>

typedef __bf16 bf16;
typedef __bf16 bf16x4 __attribute__((ext_vector_type(4)));
typedef __bf16 bf16x8 __attribute__((ext_vector_type(8)));
typedef float f32x4 __attribute__((ext_vector_type(4)));

#define NEGV -9.0e15f

#define GLD16(gp, lp)                                                    \
  __builtin_amdgcn_global_load_lds(                                     \
      (const __attribute__((address_space(1))) void*)(gp),              \
      (__attribute__((address_space(3))) void*)(lp), 16, 0, 0)

// ---------------- prep: x->bf16, Wqkv^T (col-reordered), Wo^T ----------------
// Wqkv column n = h*192 + sel*64 + d  ->  n' = sel*512 + h*64 + d
// so each 128-wide GEMM1 n-tile is purely Q, K, or V.

__global__ __launch_bounds__(256) void k_prep(
    const float* __restrict__ x, const float* __restrict__ Wqkv, const float* __restrict__ Wo,
    bf16* __restrict__ xb, bf16* __restrict__ WqkvT, bf16* __restrict__ WoT) {
  const int bid = blockIdx.x, tid = threadIdx.x;
  if (bid < 2048) {               // x convert: 2048 * 1024 floats
    int i = bid * 1024 + tid * 4;
    float4 v = *(const float4*)(x + i);
    bf16x4 o;
    o[0] = (bf16)v.x; o[1] = (bf16)v.y; o[2] = (bf16)v.z; o[3] = (bf16)v.w;
    *(bf16x4*)(xb + i) = o;
    return;
  }
  __shared__ float tl[32][33];
  const float* src; bf16* dst; int N, t; bool remap;
  if (bid < 2816) { t = bid - 2048; src = Wqkv; dst = WqkvT; N = 1536; remap = true; }
  else            { t = bid - 2816; src = Wo;   dst = WoT;   N = 512;  remap = false; }
  const int tk = t & 15, tn = t >> 4;      // k-tile (512/32), n-tile
  const int c = tid & 31, r0 = tid >> 5;
  for (int rr = 0; rr < 4; ++rr) {
    int row = r0 + rr * 8;
    tl[row][c] = src[(size_t)(tk * 32 + row) * N + tn * 32 + c];
  }
  __syncthreads();
  for (int rr = 0; rr < 4; ++rr) {
    int row = r0 + rr * 8;
    int nn = tn * 32 + row;
    int np = nn;
    if (remap) {
      int h = nn / 192, r2 = nn - h * 192, sel = r2 >> 6, d = r2 & 63;
      np = sel * 512 + h * 64 + d;
    }
    dst[(size_t)np * 512 + tk * 32 + c] = (bf16)tl[c][row];
  }
}

// ---------------- GEMM 1: qkv = x @ Wqkv + b -> Q/K/V^T ----------------
// A [4096][512] bf16, BT [1536][512] bf16 (reordered cols). BM=BN=128, BK=64.
// V n-tiles (blockIdx.y >= 8) use swapped-operand MFMA so output is transposed
// in-register -> coalesced V^T stores.

__global__ __launch_bounds__(256) void k_gemm_qkv(
    const bf16* __restrict__ A, const bf16* __restrict__ BT, const float* __restrict__ bias,
    bf16* __restrict__ Qb, bf16* __restrict__ Kb, bf16* __restrict__ VTb) {
  __shared__ __align__(16) char As[16384];   // [128 rows][64 bf16]
  __shared__ __align__(16) char Bs[16384];   // [128 rows][64 bf16]
  const int m0 = blockIdx.x * 128, n0 = blockIdx.y * 128;
  const bool isV = (blockIdx.y >= 8);
  const int tid = threadIdx.x, wave = tid >> 6, lane = tid & 63;
  const int wr = (wave >> 1) * 64, wc = (wave & 1) * 64;
  const int lr = lane & 15, lg = lane >> 4;
  const int srow = lane >> 3, scolb = (lane & 7) << 4;
  const char* Ab = (const char*)A;
  const char* Bb = (const char*)BT;
  f32x4 acc[4][4] = {};

  for (int kt = 0; kt < 512; kt += 64) {
    __syncthreads();
    for (int t = 0; t < 4; ++t) {
      int chunk = wave * 4 + t;                       // 0..15, 8 rows each
      GLD16(Ab + (size_t)(m0 + chunk * 8 + srow) * 1024 + kt * 2 + scolb,
            As + chunk * 1024);
      GLD16(Bb + (size_t)(n0 + chunk * 8 + srow) * 1024 + kt * 2 + scolb,
            Bs + chunk * 1024);
    }
    __syncthreads();
    for (int kk = 0; kk < 2; ++kk) {
      bf16x8 af[4], bfr[4];
      for (int m = 0; m < 4; ++m)
        af[m] = *(const bf16x8*)(As + (wr + m * 16 + lr) * 128 + kk * 64 + lg * 16);
      for (int n = 0; n < 4; ++n)
        bfr[n] = *(const bf16x8*)(Bs + (wc + n * 16 + lr) * 128 + kk * 64 + lg * 16);
      if (!isV) {
        for (int m = 0; m < 4; ++m)
          for (int n = 0; n < 4; ++n)
            acc[m][n] = __builtin_amdgcn_mfma_f32_16x16x32_bf16(af[m], bfr[n], acc[m][n], 0, 0, 0);
      } else {
        for (int m = 0; m < 4; ++m)
          for (int n = 0; n < 4; ++n)
            acc[m][n] = __builtin_amdgcn_mfma_f32_16x16x32_bf16(bfr[n], af[m], acc[m][n], 0, 0, 0);
      }
    }
  }

  if (!isV) {
    // C[row=s-ish][col=n'] ; col n' = n0+wc+n*16+lr, row = m0+wr+m*16+lg*4+r
    const int sel = n0 >> 9;                 // 0=Q, 1=K (uniform per block)
    bf16* Dst = sel ? Kb : Qb;
    float bv[4];
    int hh[4], dd[4];
    for (int n = 0; n < 4; ++n) {
      int gn = n0 + wc + n * 16 + lr;
      hh[n] = (gn >> 6) & 7; dd[n] = gn & 63;
      bv[n] = bias[hh[n] * 192 + sel * 64 + dd[n]];
    }
    for (int m = 0; m < 4; ++m)
      for (int r = 0; r < 4; ++r) {
        int gm = m0 + wr + m * 16 + lg * 4 + r;
        int b = gm >> 11, s = gm & 2047;
        for (int n = 0; n < 4; ++n) {
          float v = acc[m][n][r] + bv[n];
          Dst[((size_t)(b * 8 + hh[n]) * 2048 + s) * 64 + dd[n]] = (bf16)v;
        }
      }
  } else {
    // C[row=n'-ish][col=s] ; col s = m0+wr+m*16+lr, row n' = n0+wc+n*16+lg*4+r
    for (int m = 0; m < 4; ++m) {
      int gm = m0 + wr + m * 16 + lr;
      int b = gm >> 11, s = gm & 2047;
      for (int n = 0; n < 4; ++n)
        for (int r = 0; r < 4; ++r) {
          int vcol = n0 + wc + n * 16 + lg * 4 + r;
          int h = (vcol >> 6) & 7, d = vcol & 63;
          float v = acc[m][n][r] + bias[h * 192 + 128 + d];
          VTb[((size_t)(b * 8 + h) * 64 + d) * 2048 + s] = (bf16)v;
        }
    }
  }
}

// ---------------- attention ----------------
// grid (32 qblocks, 16 b*h), 256 threads (4 waves), each wave: 16 query rows

__global__ __launch_bounds__(256) void k_attn(
    const bf16* __restrict__ Qb, const bf16* __restrict__ Kb, const bf16* __restrict__ VTb,
    const int* __restrict__ pmask, bf16* __restrict__ AO) {
  __shared__ __align__(16) char Ks[128 * 128];   // [128 keys][64 d], swizzled content
  __shared__ __align__(16) char VTs[64 * 256];   // [64 d][128 s], swizzled content
  __shared__ __align__(16) char Ps[64 * 256];
  __shared__ float pmk[128];

  const int qb = blockIdx.x, bh = blockIdx.y;
  const int b = bh >> 3;
  const int q0 = qb * 64, kstart = q0 - 32;
  const int tid = threadIdx.x, wave = tid >> 6, lane = tid & 63;
  const int lr = lane & 15, lg = lane >> 4;

  const bf16* Qg = Qb + (size_t)bh * (2048 * 64);
  const bf16* Kg = Kb + (size_t)bh * (2048 * 64);
  const bf16* Vg = VTb + (size_t)bh * (64 * 2048);

  // K: 128 rows x 128B, gld_lds with pre-swizzled source col (m173 pattern)
  {
    int srow8 = lane >> 3, cb = (lane & 7) << 4;
    for (int t = 0; t < 4; ++t) {
      int chunk = wave * 4 + t;
      int row = chunk * 8 + srow8;
      int sk = kstart + row;
      sk = sk < 0 ? 0 : (sk > 2047 ? 2047 : sk);
      int csw = cb ^ ((row & 7) << 4);
      GLD16((const char*)Kg + (size_t)sk * 128 + csw, Ks + chunk * 1024);
    }
  }
  // V^T: 64 rows x 256B
  {
    int srow4 = lane >> 4, cb = (lane & 15) << 4;
    for (int t = 0; t < 4; ++t) {
      int chunk = wave * 4 + t;
      int d = chunk * 4 + srow4;
      int csw = cb ^ ((d & 7) << 4);
      int sl = kstart + (csw >> 1);
      sl = sl < 0 ? 0 : (sl > 2040 ? 2040 : sl);
      GLD16((const char*)Vg + (size_t)d * 4096 + (size_t)sl * 2, VTs + chunk * 1024);
    }
  }
  if (tid < 128) {
    int sk = kstart + tid;
    pmk[tid] = (sk >= 0 && sk < 2048 && pmask[b * 2048 + sk] != 0) ? 1.0f : 0.0f;
  }
  __syncthreads();

  // scores S = Q.K^T : 16 rows x 128 keys per wave; Q frags direct from global
  f32x4 sc[8] = {};
  for (int kk = 0; kk < 2; ++kk) {
    bf16x8 qf = *(const bf16x8*)(Qg + (size_t)(q0 + wave * 16 + lr) * 64 + kk * 32 + lg * 8);
    for (int nt = 0; nt < 8; ++nt) {
      int krow = nt * 16 + lr;
      bf16x8 kf = *(const bf16x8*)(Ks + krow * 128 + ((kk * 64 + lg * 16) ^ ((krow & 7) << 4)));
      sc[nt] = __builtin_amdgcn_mfma_f32_16x16x32_bf16(qf, kf, sc[nt], 0, 0, 0);
    }
  }

  float rmax[4] = {NEGV, NEGV, NEGV, NEGV};
  for (int nt = 0; nt < 8; ++nt) {
    int j = nt * 16 + lr;
    float pk = pmk[j];
    for (int r = 0; r < 4; ++r) {
      int qrow = wave * 16 + lg * 4 + r;
      float v = sc[nt][r] * 0.125f;
      v = (j >= qrow && j <= qrow + 64 && pk > 0.5f) ? v : NEGV;
      sc[nt][r] = v;
      rmax[r] = fmaxf(rmax[r], v);
    }
  }
  for (int off = 1; off < 16; off <<= 1)
    for (int r = 0; r < 4; ++r)
      rmax[r] = fmaxf(rmax[r], __shfl_xor(rmax[r], off));

  float rsum[4] = {0.f, 0.f, 0.f, 0.f};
  for (int nt = 0; nt < 8; ++nt)
    for (int r = 0; r < 4; ++r) {
      float p = __expf(sc[nt][r] - rmax[r]);
      sc[nt][r] = p;
      rsum[r] += p;
    }
  for (int off = 1; off < 16; off <<= 1)
    for (int r = 0; r < 4; ++r)
      rsum[r] += __shfl_xor(rsum[r], off);

  for (int nt = 0; nt < 8; ++nt)
    for (int r = 0; r < 4; ++r) {
      int qrow = wave * 16 + lg * 4 + r;
      int colb = (nt * 16 + lr) * 2;
      *(bf16*)(Ps + qrow * 256 + (colb ^ ((qrow & 7) << 4))) = (bf16)sc[nt][r];
    }
  __syncthreads();

  // O = P.V : 16 rows x 64 d per wave, K=128
  f32x4 oacc[4] = {};
  for (int ks = 0; ks < 4; ++ks) {
    int colb = ks * 64 + lg * 16;
    int prow = wave * 16 + lr;
    bf16x8 pf = *(const bf16x8*)(Ps + prow * 256 + (colb ^ ((prow & 7) << 4)));
    for (int n = 0; n < 4; ++n) {
      int vrow = n * 16 + lr;
      bf16x8 vf = *(const bf16x8*)(VTs + vrow * 256 + (colb ^ ((vrow & 7) << 4)));
      oacc[n] = __builtin_amdgcn_mfma_f32_16x16x32_bf16(pf, vf, oacc[n], 0, 0, 0);
    }
  }

  const int h = bh & 7;
  float inv[4];
  for (int r = 0; r < 4; ++r) inv[r] = 1.0f / rsum[r];
  for (int r = 0; r < 4; ++r) {
    int qrow = wave * 16 + lg * 4 + r;
    float s2 = inv[r] * pmk[32 + qrow];     // query's own pad bit lives in pmk
    for (int n = 0; n < 4; ++n)
      AO[(size_t)(b * 2048 + q0 + qrow) * 512 + h * 64 + n * 16 + lr] = (bf16)(oacc[n][r] * s2);
  }
}

// ---------------- GEMM 2: out = AO @ Wo + bo (fp32 out), BM=128 BN=64 ----------------

__global__ __launch_bounds__(256) void k_gemm_out(
    const bf16* __restrict__ A, const bf16* __restrict__ BT, const float* __restrict__ bias,
    float* __restrict__ C) {
  __shared__ __align__(16) char As[16384];
  __shared__ __align__(16) char Bs[8192];
  const int m0 = blockIdx.x * 128, n0 = blockIdx.y * 64;
  const int tid = threadIdx.x, wave = tid >> 6, lane = tid & 63;
  const int wr = (wave >> 1) * 64, wc = (wave & 1) * 32;
  const int lr = lane & 15, lg = lane >> 4;
  const int srow = lane >> 3, scolb = (lane & 7) << 4;
  const char* Ab = (const char*)A;
  const char* Bb = (const char*)BT;
  f32x4 acc[4][2] = {};

  for (int kt = 0; kt < 512; kt += 64) {
    __syncthreads();
    for (int t = 0; t < 4; ++t) {
      int chunk = wave * 4 + t;
      GLD16(Ab + (size_t)(m0 + chunk * 8 + srow) * 1024 + kt * 2 + scolb,
            As + chunk * 1024);
    }
    for (int t = 0; t < 2; ++t) {
      int chunk = wave * 2 + t;
      GLD16(Bb + (size_t)(n0 + chunk * 8 + srow) * 1024 + kt * 2 + scolb,
            Bs + chunk * 1024);
    }
    __syncthreads();
    for (int kk = 0; kk < 2; ++kk) {
      bf16x8 af[4], bfr[2];
      for (int m = 0; m < 4; ++m)
        af[m] = *(const bf16x8*)(As + (wr + m * 16 + lr) * 128 + kk * 64 + lg * 16);
      for (int n = 0; n < 2; ++n)
        bfr[n] = *(const bf16x8*)(Bs + (wc + n * 16 + lr) * 128 + kk * 64 + lg * 16);
      for (int m = 0; m < 4; ++m)
        for (int n = 0; n < 2; ++n)
          acc[m][n] = __builtin_amdgcn_mfma_f32_16x16x32_bf16(af[m], bfr[n], acc[m][n], 0, 0, 0);
    }
  }

  float bv0 = bias[n0 + wc + lr], bv1 = bias[n0 + wc + 16 + lr];
  for (int m = 0; m < 4; ++m)
    for (int n = 0; n < 2; ++n)
      for (int r = 0; r < 4; ++r) {
        int gm = m0 + wr + m * 16 + lg * 4 + r;
        int gn = n0 + wc + n * 16 + lr;
        C[(size_t)gm * 512 + gn] = acc[m][n][r] + (n ? bv1 : bv0);
      }
}

// ---------------- launch ----------------

extern "C" void kernel_launch(void* const* d_in, const int* in_sizes, int n_in,
                              void* d_out, int out_size, void* d_ws, size_t ws_size,
                              hipStream_t stream) {
  const float* x     = (const float*)d_in[0];
  const int*   pmask = (const int*)d_in[1];
  const float* Wqkv  = (const float*)d_in[2];
  const float* bqkv  = (const float*)d_in[3];
  const float* Wo    = (const float*)d_in[4];
  const float* bo    = (const float*)d_in[5];
  float* out = (float*)d_out;

  char* ws = (char*)d_ws;
  bf16* xb    = (bf16*)(ws);                 // 4096*512*2   = 4 MiB
  bf16* WqkvT = (bf16*)(ws + 4194304);       // 1536*512*2   = 1.5 MiB (reordered)
  bf16* WoT   = (bf16*)(ws + 5767168);       // 512*512*2    = 0.5 MiB
  bf16* Qb    = (bf16*)(ws + 6291456);       // [b][h][s][d] = 4 MiB
  bf16* Kb    = (bf16*)(ws + 10485760);      // [b][h][s][d] = 4 MiB
  bf16* VTb   = (bf16*)(ws + 14680064);      // [b][h][d][s] = 4 MiB
  bf16* AO    = (bf16*)(ws + 18874368);      // [b][s][h*d]  = 4 MiB

  k_prep<<<3072, 256, 0, stream>>>(x, Wqkv, Wo, xb, WqkvT, WoT);

  dim3 g1(32, 12);
  k_gemm_qkv<<<g1, 256, 0, stream>>>(xb, WqkvT, bqkv, Qb, Kb, VTb);

  dim3 ga(32, 16);
  k_attn<<<ga, 256, 0, stream>>>(Qb, Kb, VTb, pmask, AO);

  dim3 g2(32, 8);
  k_gemm_out<<<g2, 256, 0, stream>>>(AO, WoT, bo, out);
}

// Round 4
// 44.478 us; speedup vs baseline: 1.2339x; 1.2339x over previous
//
#include <hip/hip_runtime.h>
#include <hip/hip_bf16.h>

typedef __bf16 bf16;
typedef __bf16 bf16x4 __attribute__((ext_vector_type(4)));
typedef __bf16 bf16x8 __attribute__((ext_vector_type(8)));
typedef float f32x4 __attribute__((ext_vector_type(4)));

#define NEGV -9.0e15f

#define GLD16(gp, lp)                                                    \
  __builtin_amdgcn_global_load_lds(                                     \
      (const __attribute__((address_space(1))) void*)(gp),              \
      (__attribute__((address_space(3))) void*)(lp), 16, 0, 0)

// ---------------- prep: x->bf16, Wqkv^T (col-reordered), Wo^T ----------------
// Wqkv column n = h*192 + sel*64 + d  ->  n' = sel*512 + h*64 + d
// so each 64-wide GEMM1 n-tile is purely Q, K, or V.

__global__ __launch_bounds__(256) void k_prep(
    const float* __restrict__ x, const float* __restrict__ Wqkv, const float* __restrict__ Wo,
    bf16* __restrict__ xb, bf16* __restrict__ WqkvT, bf16* __restrict__ WoT) {
  const int bid = blockIdx.x, tid = threadIdx.x;
  if (bid < 2048) {               // x convert: 2048 * 1024 floats
    int i = bid * 1024 + tid * 4;
    float4 v = *(const float4*)(x + i);
    bf16x4 o;
    o[0] = (bf16)v.x; o[1] = (bf16)v.y; o[2] = (bf16)v.z; o[3] = (bf16)v.w;
    *(bf16x4*)(xb + i) = o;
    return;
  }
  __shared__ float tl[32][33];
  const float* src; bf16* dst; int N, t; bool remap;
  if (bid < 2816) { t = bid - 2048; src = Wqkv; dst = WqkvT; N = 1536; remap = true; }
  else            { t = bid - 2816; src = Wo;   dst = WoT;   N = 512;  remap = false; }
  const int tk = t & 15, tn = t >> 4;      // k-tile (512/32), n-tile
  const int c = tid & 31, r0 = tid >> 5;
  for (int rr = 0; rr < 4; ++rr) {
    int row = r0 + rr * 8;
    tl[row][c] = src[(size_t)(tk * 32 + row) * N + tn * 32 + c];
  }
  __syncthreads();
  for (int rr = 0; rr < 4; ++rr) {
    int row = r0 + rr * 8;
    int nn = tn * 32 + row;
    int np = nn;
    if (remap) {
      int h = nn / 192, r2 = nn - h * 192, sel = r2 >> 6, d = r2 & 63;
      np = sel * 512 + h * 64 + d;
    }
    dst[(size_t)np * 512 + tk * 32 + c] = (bf16)tl[c][row];
  }
}

// ---------------- GEMM 1: qkv = x @ Wqkv + b -> Q/K/V^T ----------------
// A [4096][512] bf16, BT [1536][512] bf16 (reordered cols). BM=128, BN=64, BK=64.
// Grid (32,24) = 768 blocks = exactly 3/CU. blockIdx.y>>3 = 0:Q 1:K 2:V.
// V tiles: swapped-operand MFMA -> transposed tile in-register -> coalesced VT stores.

__global__ __launch_bounds__(256) void k_gemm_qkv(
    const bf16* __restrict__ A, const bf16* __restrict__ BT, const float* __restrict__ bias,
    bf16* __restrict__ Qb, bf16* __restrict__ Kb, bf16* __restrict__ VTb) {
  __shared__ __align__(16) char As[16384];   // [128 rows][64 bf16]
  __shared__ __align__(16) char Bs[8192];    // [64 rows][64 bf16]
  const int m0 = blockIdx.x * 128, n0 = blockIdx.y * 64;
  const int sel = blockIdx.y >> 3;           // 0=Q 1=K 2=V, uniform per block
  const bool isV = (sel == 2);
  const int tid = threadIdx.x, wave = tid >> 6, lane = tid & 63;
  const int wr = (wave >> 1) * 64, wc = (wave & 1) * 32;
  const int lr = lane & 15, lg = lane >> 4;
  const int srow = lane >> 3, scolb = (lane & 7) << 4;
  const char* Ab = (const char*)A;
  const char* Bb = (const char*)BT;
  f32x4 acc[4][2] = {};

  for (int kt = 0; kt < 512; kt += 64) {
    __syncthreads();
    for (int t = 0; t < 4; ++t) {
      int chunk = wave * 4 + t;                       // 0..15, 8 rows each
      GLD16(Ab + (size_t)(m0 + chunk * 8 + srow) * 1024 + kt * 2 + scolb,
            As + chunk * 1024);
    }
    for (int t = 0; t < 2; ++t) {
      int chunk = wave * 2 + t;                       // 0..7
      GLD16(Bb + (size_t)(n0 + chunk * 8 + srow) * 1024 + kt * 2 + scolb,
            Bs + chunk * 1024);
    }
    __syncthreads();
    for (int kk = 0; kk < 2; ++kk) {
      bf16x8 af[4], bfr[2];
      for (int m = 0; m < 4; ++m)
        af[m] = *(const bf16x8*)(As + (wr + m * 16 + lr) * 128 + kk * 64 + lg * 16);
      for (int n = 0; n < 2; ++n)
        bfr[n] = *(const bf16x8*)(Bs + (wc + n * 16 + lr) * 128 + kk * 64 + lg * 16);
      if (!isV) {
        for (int m = 0; m < 4; ++m)
          for (int n = 0; n < 2; ++n)
            acc[m][n] = __builtin_amdgcn_mfma_f32_16x16x32_bf16(af[m], bfr[n], acc[m][n], 0, 0, 0);
      } else {
        for (int m = 0; m < 4; ++m)
          for (int n = 0; n < 2; ++n)
            acc[m][n] = __builtin_amdgcn_mfma_f32_16x16x32_bf16(bfr[n], af[m], acc[m][n], 0, 0, 0);
      }
    }
  }

  if (!isV) {
    // C row = gm (x-row), col = gn (weight col n')
    bf16* Dst = sel ? Kb : Qb;
    float bv[2]; int hh[2], dd[2];
    for (int n = 0; n < 2; ++n) {
      int gn = n0 + wc + n * 16 + lr;
      hh[n] = (gn >> 6) & 7; dd[n] = gn & 63;
      bv[n] = bias[hh[n] * 192 + sel * 64 + dd[n]];
    }
    for (int m = 0; m < 4; ++m)
      for (int r = 0; r < 4; ++r) {
        int gm = m0 + wr + m * 16 + lg * 4 + r;
        int b = gm >> 11, s = gm & 2047;
        for (int n = 0; n < 2; ++n) {
          float v = acc[m][n][r] + bv[n];
          Dst[((size_t)(b * 8 + hh[n]) * 2048 + s) * 64 + dd[n]] = (bf16)v;
        }
      }
  } else {
    // swapped: C row = gn (weight col n'), col = gm (x-row s) -> s contiguous over lr
    for (int m = 0; m < 4; ++m) {
      int gm = m0 + wr + m * 16 + lr;
      int b = gm >> 11, s = gm & 2047;
      for (int n = 0; n < 2; ++n)
        for (int r = 0; r < 4; ++r) {
          int gn = n0 + wc + n * 16 + lg * 4 + r;   // in [1024,1536)
          int h = (gn >> 6) & 7, d = gn & 63;
          float v = acc[m][n][r] + bias[h * 192 + 128 + d];
          VTb[((size_t)(b * 8 + h) * 64 + d) * 2048 + s] = (bf16)v;
        }
    }
  }
}

// ---------------- attention (round-2 version, known-good) ----------------
// grid (32 qblocks, 16 b*h), 256 threads (4 waves), each wave: 16 query rows

__global__ __launch_bounds__(256) void k_attn(
    const bf16* __restrict__ Qb, const bf16* __restrict__ Kb, const bf16* __restrict__ VTb,
    const int* __restrict__ pmask, bf16* __restrict__ AO) {
  __shared__ __align__(16) char Qs[64 * 128];
  __shared__ __align__(16) char Ks[128 * 128];
  __shared__ __align__(16) char VTs[64 * 256];
  __shared__ __align__(16) char Ps[64 * 256];
  __shared__ float pmk[128];

  const int qb = blockIdx.x, bh = blockIdx.y;
  const int b = bh >> 3, h = bh & 7;
  const int q0 = qb * 64, kstart = q0 - 32;
  const int tid = threadIdx.x, wave = tid >> 6, lane = tid & 63;
  const int lr = lane & 15, lg = lane >> 4;

  const bf16* Qg = Qb + (size_t)bh * (2048 * 64);
  const bf16* Kg = Kb + (size_t)bh * (2048 * 64);
  const bf16* Vg = VTb + (size_t)bh * (64 * 2048);

  for (int c = tid; c < 512; c += 256) {
    int row = c >> 3, colb = (c & 7) << 4;
    *(uint4*)(Qs + row * 128 + (colb ^ ((row & 7) << 4))) =
        *(const uint4*)((const char*)Qg + (size_t)(q0 + row) * 128 + colb);
  }
  for (int c = tid; c < 1024; c += 256) {
    int row = c >> 3, colb = (c & 7) << 4;
    int sk = kstart + row;
    sk = sk < 0 ? 0 : (sk > 2047 ? 2047 : sk);
    *(uint4*)(Ks + row * 128 + (colb ^ ((row & 7) << 4))) =
        *(const uint4*)((const char*)Kg + (size_t)sk * 128 + colb);
  }
  for (int c = tid; c < 1024; c += 256) {
    int d = c >> 4, colb = (c & 15) << 4;
    int sl = kstart + (colb >> 1);
    sl = sl < 0 ? 0 : (sl > 2040 ? 2040 : sl);
    *(uint4*)(VTs + d * 256 + (colb ^ ((d & 7) << 4))) =
        *(const uint4*)((const char*)Vg + (size_t)d * 4096 + (size_t)sl * 2);
  }
  if (tid < 128) {
    int sk = kstart + tid;
    pmk[tid] = (sk >= 0 && sk < 2048 && pmask[b * 2048 + sk] != 0) ? 1.0f : 0.0f;
  }
  __syncthreads();

  // scores S = Q.K^T : 16 rows x 128 keys per wave
  f32x4 sc[8] = {};
  for (int kk = 0; kk < 2; ++kk) {
    int colb = kk * 64 + lg * 16;
    int qrow = wave * 16 + lr;
    bf16x8 qf = *(const bf16x8*)(Qs + qrow * 128 + (colb ^ ((qrow & 7) << 4)));
    for (int nt = 0; nt < 8; ++nt) {
      int krow = nt * 16 + lr;
      bf16x8 kf = *(const bf16x8*)(Ks + krow * 128 + (colb ^ ((krow & 7) << 4)));
      sc[nt] = __builtin_amdgcn_mfma_f32_16x16x32_bf16(qf, kf, sc[nt], 0, 0, 0);
    }
  }

  float rmax[4] = {NEGV, NEGV, NEGV, NEGV};
  for (int nt = 0; nt < 8; ++nt) {
    int j = nt * 16 + lr;
    float pk = pmk[j];
    for (int r = 0; r < 4; ++r) {
      int qrow = wave * 16 + lg * 4 + r;
      float v = sc[nt][r] * 0.125f;
      v = (j >= qrow && j <= qrow + 64 && pk > 0.5f) ? v : NEGV;
      sc[nt][r] = v;
      rmax[r] = fmaxf(rmax[r], v);
    }
  }
  for (int off = 1; off < 16; off <<= 1)
    for (int r = 0; r < 4; ++r)
      rmax[r] = fmaxf(rmax[r], __shfl_xor(rmax[r], off));

  float rsum[4] = {0.f, 0.f, 0.f, 0.f};
  for (int nt = 0; nt < 8; ++nt)
    for (int r = 0; r < 4; ++r) {
      float p = __expf(sc[nt][r] - rmax[r]);
      sc[nt][r] = p;
      rsum[r] += p;
    }
  for (int off = 1; off < 16; off <<= 1)
    for (int r = 0; r < 4; ++r)
      rsum[r] += __shfl_xor(rsum[r], off);

  for (int nt = 0; nt < 8; ++nt)
    for (int r = 0; r < 4; ++r) {
      int qrow = wave * 16 + lg * 4 + r;
      int colb = (nt * 16 + lr) * 2;
      *(bf16*)(Ps + qrow * 256 + (colb ^ ((qrow & 7) << 4))) = (bf16)sc[nt][r];
    }
  __syncthreads();

  // O = P.V : 16 rows x 64 d per wave, K=128
  f32x4 oacc[4] = {};
  for (int ks = 0; ks < 4; ++ks) {
    int colb = ks * 64 + lg * 16;
    int prow = wave * 16 + lr;
    bf16x8 pf = *(const bf16x8*)(Ps + prow * 256 + (colb ^ ((prow & 7) << 4)));
    for (int n = 0; n < 4; ++n) {
      int vrow = n * 16 + lr;
      bf16x8 vf = *(const bf16x8*)(VTs + vrow * 256 + (colb ^ ((vrow & 7) << 4)));
      oacc[n] = __builtin_amdgcn_mfma_f32_16x16x32_bf16(pf, vf, oacc[n], 0, 0, 0);
    }
  }

  float inv[4];
  for (int r = 0; r < 4; ++r) inv[r] = 1.0f / rsum[r];
  for (int r = 0; r < 4; ++r) {
    int qrow = wave * 16 + lg * 4 + r;
    float s2 = inv[r] * pmk[32 + qrow];
    for (int n = 0; n < 4; ++n)
      AO[(size_t)(b * 2048 + q0 + qrow) * 512 + h * 64 + n * 16 + lr] = (bf16)(oacc[n][r] * s2);
  }
}

// ---------------- GEMM 2: out = AO @ Wo + bo (fp32 out), BM=128 BN=64 ----------------

__global__ __launch_bounds__(256) void k_gemm_out(
    const bf16* __restrict__ A, const bf16* __restrict__ BT, const float* __restrict__ bias,
    float* __restrict__ C) {
  __shared__ __align__(16) char As[16384];
  __shared__ __align__(16) char Bs[8192];
  const int m0 = blockIdx.x * 128, n0 = blockIdx.y * 64;
  const int tid = threadIdx.x, wave = tid >> 6, lane = tid & 63;
  const int wr = (wave >> 1) * 64, wc = (wave & 1) * 32;
  const int lr = lane & 15, lg = lane >> 4;
  const int srow = lane >> 3, scolb = (lane & 7) << 4;
  const char* Ab = (const char*)A;
  const char* Bb = (const char*)BT;
  f32x4 acc[4][2] = {};

  for (int kt = 0; kt < 512; kt += 64) {
    __syncthreads();
    for (int t = 0; t < 4; ++t) {
      int chunk = wave * 4 + t;
      GLD16(Ab + (size_t)(m0 + chunk * 8 + srow) * 1024 + kt * 2 + scolb,
            As + chunk * 1024);
    }
    for (int t = 0; t < 2; ++t) {
      int chunk = wave * 2 + t;
      GLD16(Bb + (size_t)(n0 + chunk * 8 + srow) * 1024 + kt * 2 + scolb,
            Bs + chunk * 1024);
    }
    __syncthreads();
    for (int kk = 0; kk < 2; ++kk) {
      bf16x8 af[4], bfr[2];
      for (int m = 0; m < 4; ++m)
        af[m] = *(const bf16x8*)(As + (wr + m * 16 + lr) * 128 + kk * 64 + lg * 16);
      for (int n = 0; n < 2; ++n)
        bfr[n] = *(const bf16x8*)(Bs + (wc + n * 16 + lr) * 128 + kk * 64 + lg * 16);
      for (int m = 0; m < 4; ++m)
        for (int n = 0; n < 2; ++n)
          acc[m][n] = __builtin_amdgcn_mfma_f32_16x16x32_bf16(af[m], bfr[n], acc[m][n], 0, 0, 0);
    }
  }

  float bv0 = bias[n0 + wc + lr], bv1 = bias[n0 + wc + 16 + lr];
  for (int m = 0; m < 4; ++m)
    for (int n = 0; n < 2; ++n)
      for (int r = 0; r < 4; ++r) {
        int gm = m0 + wr + m * 16 + lg * 4 + r;
        int gn = n0 + wc + n * 16 + lr;
        C[(size_t)gm * 512 + gn] = acc[m][n][r] + (n ? bv1 : bv0);
      }
}

// ---------------- launch ----------------

extern "C" void kernel_launch(void* const* d_in, const int* in_sizes, int n_in,
                              void* d_out, int out_size, void* d_ws, size_t ws_size,
                              hipStream_t stream) {
  const float* x     = (const float*)d_in[0];
  const int*   pmask = (const int*)d_in[1];
  const float* Wqkv  = (const float*)d_in[2];
  const float* bqkv  = (const float*)d_in[3];
  const float* Wo    = (const float*)d_in[4];
  const float* bo    = (const float*)d_in[5];
  float* out = (float*)d_out;

  char* ws = (char*)d_ws;
  bf16* xb    = (bf16*)(ws);                 // 4096*512*2   = 4 MiB
  bf16* WqkvT = (bf16*)(ws + 4194304);       // 1536*512*2   = 1.5 MiB (reordered)
  bf16* WoT   = (bf16*)(ws + 5767168);       // 512*512*2    = 0.5 MiB
  bf16* Qb    = (bf16*)(ws + 6291456);       // [b][h][s][d] = 4 MiB
  bf16* Kb    = (bf16*)(ws + 10485760);      // [b][h][s][d] = 4 MiB
  bf16* VTb   = (bf16*)(ws + 14680064);      // [b][h][d][s] = 4 MiB
  bf16* AO    = (bf16*)(ws + 18874368);      // [b][s][h*d]  = 4 MiB

  k_prep<<<3072, 256, 0, stream>>>(x, Wqkv, Wo, xb, WqkvT, WoT);

  dim3 g1(32, 24);
  k_gemm_qkv<<<g1, 256, 0, stream>>>(xb, WqkvT, bqkv, Qb, Kb, VTb);

  dim3 ga(32, 16);
  k_attn<<<ga, 256, 0, stream>>>(Qb, Kb, VTb, pmask, AO);

  dim3 g2(32, 8);
  k_gemm_out<<<g2, 256, 0, stream>>>(AO, WoT, bo, out);
}